// Round 8
// baseline (217.674 us; speedup 1.0000x reference)
//
#include <hip/hip_runtime.h>

// Problem constants (fixed-shape bench)
#define B_ 4
#define K_ 64
#define R_ 16
#define H_ 16
#define S_ 2048

typedef float f32x4 __attribute__((ext_vector_type(4)));

// ---------------------------------------------------------------------------
// Kernel A: one block per (b,h). Grid (B,H) = 64 blocks, 256 thr.
// adj is only 1 MB total -> every block reads adj[b] (256 KB), L2-resident.
// s[j][r] = sum_i adj[b,i,j,r]; anchor[j] = (1/K) sum_r s[j][r] W[r][h];
// colval[b,h,:] = 0 then parallel scatter with last-occurrence-wins mask
// (numpy fancy-assignment duplicate semantics).
// ---------------------------------------------------------------------------
__global__ __launch_bounds__(256) void finalize_colval_kernel(
    const f32x4* __restrict__ adj4,    // [B*K, 256]  (= [B,K,K,R] /4)
    const float* __restrict__ W,       // [R,H]
    const int*   __restrict__ idx,     // [B,K]
    float*       __restrict__ colval)  // [B,H,S]
{
    __shared__ float s_jr[K_ * R_];   // s[j][r], q = j*R+r flattened
    __shared__ float s_anchor[K_];
    __shared__ int   s_idx[K_];
    __shared__ int   s_win[K_];

    const int b   = blockIdx.x;
    const int h   = blockIdx.y;
    const int tid = threadIdx.x;

    // Column-sum over i: 64 loads at 4 KB stride, coalesced across threads.
    const f32x4* ab = adj4 + (size_t)b * K_ * 256;
    f32x4 acc = (f32x4)(0.f);
    #pragma unroll
    for (int i = 0; i < K_; ++i)
        acc += ab[i * 256 + tid];
    reinterpret_cast<f32x4*>(s_jr)[tid] = acc;

    if (tid < K_) s_idx[tid] = idx[b * K_ + tid];

    // Zero this (b,h) colval row: S floats = 512 f32x4.
    f32x4* cv4 = reinterpret_cast<f32x4*>(colval + ((size_t)b * H_ + h) * S_);
    cv4[tid]       = (f32x4)(0.f);
    cv4[tid + 256] = (f32x4)(0.f);
    __syncthreads();

    if (tid < K_) {
        float a = 0.f;
        #pragma unroll
        for (int r = 0; r < R_; ++r)
            a += s_jr[tid * R_ + r] * W[r * H_ + h];
        s_anchor[tid] = a * (1.0f / K_);
        // winner = last occurrence of this index value
        const int c = s_idx[tid];
        int win = 1;
        for (int k2 = tid + 1; k2 < K_; ++k2)
            win &= (s_idx[k2] != c);
        s_win[tid] = win;
    }
    __syncthreads();

    if (tid < K_ && s_win[tid]) {
        colval[((size_t)b * H_ + h) * S_ + s_idx[tid]] = s_anchor[tid];
    }
}

// ---------------------------------------------------------------------------
// Kernel B: fill-pattern sweep. 1024 blocks x 512 thr, grid-stride in f32x4:
// thread T owns column (T&511); block g writes row g, g+1024, g+2048, ...
// => at every instant the WHOLE grid writes one contiguous 8 MB band that
// sweeps the 1 GB output linearly — exactly the rocclr fill kernel's
// frontier (6.6 TB/s), vs R6's 1024 scattered 1 MB chunk frontiers.
// v reloads from L2 only when bh changes (uniform branch, every 2 iters).
// ---------------------------------------------------------------------------
__global__ __launch_bounds__(512) void broadcast_sweep_kernel(
    const f32x4* __restrict__ colval4,  // [B*H, S/4]
    f32x4*       __restrict__ out4)     // [B*H * S, S/4] flat
{
    const int col4 = threadIdx.x;               // 0..511 (= S/4)
    const int g    = blockIdx.x;                // 0..1023 starting row

    // rows per sweep step = gridDim (1024); total rows = B*H*S = 131072
    // iterations = 131072 / 1024 = 128; bh = row >> 11 = it >> 1.
    f32x4 v = colval4[col4];                    // bh = 0 initially
    int bh = 0;

    f32x4* p = out4 + (size_t)g * (S_ / 4) + col4;
    const size_t step = (size_t)1024 * (S_ / 4);   // 8 MB / 16B = 524288

    #pragma unroll 8
    for (int it = 0; it < 128; ++it) {
        const int nbh = it >> 1;                 // uniform across block
        if (nbh != bh) {
            bh = nbh;
            v = colval4[bh * (S_ / 4) + col4];
        }
        *p = v;
        p += step;
    }
}

extern "C" void kernel_launch(void* const* d_in, const int* in_sizes, int n_in,
                              void* d_out, int out_size, void* d_ws, size_t ws_size,
                              hipStream_t stream) {
    const float* adj = (const float*)d_in[0];   // [B,K,K,R] fp32 (1 MB)
    const float* W   = (const float*)d_in[1];   // [R,H] fp32
    const int*   idx = (const int*)d_in[2];     // [B,K] int32
    // d_in[3] = seq_l scalar (2048), hardcoded as S_.

    float* out    = (float*)d_out;
    float* colval = (float*)d_ws;               // B*H*S fp32 = 512 KB scratch

    dim3 gA(B_, H_);                            // 64 blocks
    finalize_colval_kernel<<<gA, 256, 0, stream>>>(
        (const f32x4*)adj, W, idx, colval);

    broadcast_sweep_kernel<<<1024, 512, 0, stream>>>(
        (const f32x4*)colval, (f32x4*)out);
}

// Round 9
// 194.943 us; speedup vs baseline: 1.1166x; 1.1166x over previous
//
#include <hip/hip_runtime.h>

// Problem constants (fixed-shape bench)
#define B_ 4
#define K_ 64
#define R_ 16
#define H_ 16
#define S_ 2048
#define ROWS_PER_BLOCK 128   // rows per block in broadcast: grid.x = 16

typedef float f32x4 __attribute__((ext_vector_type(4)));

// ---------------------------------------------------------------------------
// Kernel A: one block per (b,h). Grid (B,H) = 64 blocks, 256 thr.
// adj is only 1 MB total -> every block reads adj[b] (256 KB), L2-resident.
// s[j][r] = sum_i adj[b,i,j,r]; anchor[j] = (1/K) sum_r s[j][r] W[r][h];
// colval[b,h,:] = 0 then parallel scatter with last-occurrence-wins mask
// (numpy fancy-assignment duplicate semantics).
// ---------------------------------------------------------------------------
__global__ __launch_bounds__(256) void finalize_colval_kernel(
    const f32x4* __restrict__ adj4,    // [B*K, 256]  (= [B,K,K,R] /4)
    const float* __restrict__ W,       // [R,H]
    const int*   __restrict__ idx,     // [B,K]
    float*       __restrict__ colval)  // [B,H,S]
{
    __shared__ float s_jr[K_ * R_];   // s[j][r], q = j*R+r flattened
    __shared__ float s_anchor[K_];
    __shared__ int   s_idx[K_];
    __shared__ int   s_win[K_];

    const int b   = blockIdx.x;
    const int h   = blockIdx.y;
    const int tid = threadIdx.x;

    // Column-sum over i: 64 loads at 4 KB stride, coalesced across threads.
    const f32x4* ab = adj4 + (size_t)b * K_ * 256;
    f32x4 acc = (f32x4)(0.f);
    #pragma unroll
    for (int i = 0; i < K_; ++i)
        acc += ab[i * 256 + tid];
    reinterpret_cast<f32x4*>(s_jr)[tid] = acc;

    if (tid < K_) s_idx[tid] = idx[b * K_ + tid];

    // Zero this (b,h) colval row: S floats = 512 f32x4.
    f32x4* cv4 = reinterpret_cast<f32x4*>(colval + ((size_t)b * H_ + h) * S_);
    cv4[tid]       = (f32x4)(0.f);
    cv4[tid + 256] = (f32x4)(0.f);
    __syncthreads();

    if (tid < K_) {
        float a = 0.f;
        #pragma unroll
        for (int r = 0; r < R_; ++r)
            a += s_jr[tid * R_ + r] * W[r * H_ + h];
        s_anchor[tid] = a * (1.0f / K_);
        // winner = last occurrence of this index value
        const int c = s_idx[tid];
        int win = 1;
        for (int k2 = tid + 1; k2 < K_; ++k2)
            win &= (s_idx[k2] != c);
        s_win[tid] = win;
    }
    __syncthreads();

    if (tid < K_ && s_win[tid]) {
        colval[((size_t)b * H_ + h) * S_ + s_idx[tid]] = s_anchor[tid];
    }
}

// ---------------------------------------------------------------------------
// Kernel B: streaming broadcast (measured-best R6 shape).
// Grid (16,64) = 1024 blocks x 512 thr = 4 blocks/CU (full residency, one
// generation). Each thread owns one f32x4 column, walks 128 rows in a
// monotone stream (per wave: contiguous 1 KB bursts at 8 KB stride).
// Measured-negative variants (do not reintroduce):
//   nontemporal stores (R3, +10%), per-block row-phase rotation (R7, +9%),
//   grid-stride fill-pattern sweep (R8, +12%).
// Fitted model: steady ~6.95 TB/s + ~32 us fixed dispatch overhead — this
// kernel already matches the rocclr fill kernel's steady-state rate.
// ---------------------------------------------------------------------------
__global__ __launch_bounds__(512) void broadcast_rows_kernel(
    const f32x4* __restrict__ colval4,  // [B*H, S/4]
    f32x4*       __restrict__ out4)     // [B*H, S, S/4]
{
    const int bh   = blockIdx.y;
    const int row0 = blockIdx.x * ROWS_PER_BLOCK;
    const int t    = threadIdx.x;        // 0..511 == S/4

    const f32x4 v = colval4[bh * (S_ / 4) + t];

    f32x4* base = out4 + ((size_t)bh * S_ + row0) * (S_ / 4) + t;
    #pragma unroll 16
    for (int r = 0; r < ROWS_PER_BLOCK; ++r) {
        base[(size_t)r * (S_ / 4)] = v;
    }
}

extern "C" void kernel_launch(void* const* d_in, const int* in_sizes, int n_in,
                              void* d_out, int out_size, void* d_ws, size_t ws_size,
                              hipStream_t stream) {
    const float* adj = (const float*)d_in[0];   // [B,K,K,R] fp32 (1 MB)
    const float* W   = (const float*)d_in[1];   // [R,H] fp32
    const int*   idx = (const int*)d_in[2];     // [B,K] int32
    // d_in[3] = seq_l scalar (2048), hardcoded as S_.

    float* out    = (float*)d_out;
    float* colval = (float*)d_ws;               // B*H*S fp32 = 512 KB scratch

    dim3 gA(B_, H_);                            // 64 blocks
    finalize_colval_kernel<<<gA, 256, 0, stream>>>(
        (const f32x4*)adj, W, idx, colval);

    dim3 gB(S_ / ROWS_PER_BLOCK, B_ * H_);      // (16, 64) = 1024 blocks
    broadcast_rows_kernel<<<gB, 512, 0, stream>>>(
        (const f32x4*)colval, (f32x4*)out);
}